// Round 1
// baseline (877.098 us; speedup 1.0000x reference)
//
#include <hip/hip_runtime.h>
#include <cstdint>
#include <cstddef>

// Conv2d 3x3 s1 p1: N=16, CI=64, CO=128, H=W=224, fp32 in/out.
// Strategy: implicit GEMM with bf16 MFMA (fp32 accum).
//   GEMM: out[co][(n,h,w)] = sum_k wr[co][k] * patch[k][(n,h,w)],
//   k = tap*64 + ci  (tap = kh*3+kw) so 8-consecutive-k fragment reads are
//   ci-contiguous in an LDS tile stored as [row][ciblk][w+halo][8ci].

typedef short bf16x8 __attribute__((ext_vector_type(8)));
typedef float f32x4 __attribute__((ext_vector_type(4)));

#define N_ 16
#define CI_ 64
#define CO_ 128
#define H_ 224
#define W_ 224
#define HW_ (H_ * W_)

__device__ __forceinline__ unsigned short f2bf(float f) {
    unsigned u = __builtin_bit_cast(unsigned, f);
    u += 0x7FFFu + ((u >> 16) & 1u);   // round-to-nearest-even
    return (unsigned short)(u >> 16);
}

// weight [CO][CI][3][3] fp32 -> wr[t][co][ci] bf16  (t = kh*3+kw)
__global__ void prep_weight(const float* __restrict__ w, unsigned short* __restrict__ wr) {
    int i = blockIdx.x * 256 + threadIdx.x;          // i = t*8192 + co*64 + ci
    if (i >= 9 * CO_ * CI_) return;
    int ci = i & 63;
    int co = (i >> 6) & 127;
    int t  = i >> 13;
    wr[i] = f2bf(w[(co * CI_ + ci) * 9 + t]);
}

// One WG (512 thr, 8 waves) computes out[n][0:128][h0:h0+2][0:224].
// Wave tile: 64 co x 112 w on one h row. K loop: 2 ci-halves x 9 taps.
__global__ __launch_bounds__(512, 2) void conv_mfma(
    const float* __restrict__ x, const unsigned short* __restrict__ wr,
    const float* __restrict__ bias, float* __restrict__ out)
{
    // xs[r4(4)][cb(4)][wp(226)][8 ci] bf16 = 57,856 B
    __shared__ unsigned short xs[4 * 4 * 226 * 8];

    int bid = blockIdx.x;
    // bijective XCD swizzle: 1792 = 8 * 224
    int swz = (bid & 7) * 224 + (bid >> 3);
    int n    = swz / 112;
    int hblk = swz - n * 112;
    int h0 = hblk * 2;

    int tid  = threadIdx.x;
    int lane = tid & 63;
    int wid  = tid >> 6;
    int hr = wid & 1;          // h row within WG
    int nh = (wid >> 1) & 1;   // w half
    int mh = wid >> 2;         // co half

    int lrow = lane & 15;      // A row / B col / D col
    int lk   = lane >> 4;      // k group (8 ci each)

    f32x4 acc[4][7];
    #pragma unroll
    for (int a = 0; a < 4; ++a)
        #pragma unroll
        for (int b = 0; b < 7; ++b)
            #pragma unroll
            for (int k = 0; k < 4; ++k)
                acc[a][b][k] = 0.0f;

    for (int ch = 0; ch < 2; ++ch) {
        if (ch) __syncthreads();

        // ---- stage 4 input rows x 32 ci x 224 w (fp32 -> bf16, transposed) ----
        const float* xb = x + ((size_t)n * CI_ + (size_t)ch * 32) * HW_;
        int wcol = tid % 224;
        int rem  = tid / 224;
        for (int it = 0; it < 7; ++it) {
            float v[8]; int bi[8];
            #pragma unroll
            for (int u = 0; u < 8; ++u) {
                int ciL = rem & 31;
                int r4  = rem >> 5;
                int hh  = h0 - 1 + r4;
                float val = 0.0f;
                if ((unsigned)hh < (unsigned)H_)
                    val = xb[(size_t)ciL * HW_ + (size_t)hh * W_ + wcol];
                v[u]  = val;
                bi[u] = (((r4 << 2) + (ciL >> 3)) * 226 + wcol + 1) * 8 + (ciL & 7);
                wcol += 64; rem += 2;
                if (wcol >= 224) { wcol -= 224; rem += 1; }
            }
            #pragma unroll
            for (int u = 0; u < 8; ++u)
                xs[bi[u]] = f2bf(v[u]);
        }
        // halo columns wp=0 and wp=225 -> zero  (256 slots)
        if (tid < 256) {
            int wp  = (tid & 1) * 225;
            int ciL = (tid >> 1) & 31;
            int r4  = tid >> 6;
            xs[(((r4 << 2) + (ciL >> 3)) * 226 + wp) * 8 + (ciL & 7)] = 0;
        }
        __syncthreads();

        // ---- 9 taps x 1 k-step(32) each ----
        #pragma unroll
        for (int t = 0; t < 9; ++t) {
            int kh = t / 3, kw = t - kh * 3;
            bf16x8 afr[4];
            #pragma unroll
            for (int mf = 0; mf < 4; ++mf) {
                size_t ai = ((size_t)(t * 128 + mh * 64 + mf * 16 + lrow)) * 64
                          + (size_t)(ch * 32 + lk * 8);
                afr[mf] = *(const bf16x8*)(wr + ai);
            }
            int rbase = ((hr + kh) * 4 + lk) * 226;
            int wpb   = nh * 112 + lrow + kw;   // wp = w + kw - 1 + 1(halo)
            #pragma unroll
            for (int nf = 0; nf < 7; ++nf) {
                bf16x8 bfr = *(const bf16x8*)(&xs[(size_t)(rbase + wpb + nf * 16) * 8]);
                #pragma unroll
                for (int mf = 0; mf < 4; ++mf)
                    acc[mf][nf] = __builtin_amdgcn_mfma_f32_16x16x32_bf16(
                        afr[mf], bfr, acc[mf][nf], 0, 0, 0);
            }
        }
    }

    // ---- epilogue: bias + store ----
    int h = h0 + hr;
    #pragma unroll
    for (int mf = 0; mf < 4; ++mf) {
        #pragma unroll
        for (int r = 0; r < 4; ++r) {
            int co = mh * 64 + mf * 16 + lk * 4 + r;
            float bv = bias[co];
            size_t ob = (((size_t)n * CO_ + co) * H_ + h) * W_ + nh * 112 + lrow;
            #pragma unroll
            for (int nf = 0; nf < 7; ++nf)
                out[ob + (size_t)nf * 16] = acc[mf][nf][r] + bv;
        }
    }
}

extern "C" void kernel_launch(void* const* d_in, const int* in_sizes, int n_in,
                              void* d_out, int out_size, void* d_ws, size_t ws_size,
                              hipStream_t stream) {
    const float* x    = (const float*)d_in[0];
    const float* w    = (const float*)d_in[1];
    const float* bias = (const float*)d_in[2];
    float* out = (float*)d_out;
    unsigned short* wr = (unsigned short*)d_ws;   // 9*128*64*2 = 147,456 B

    prep_weight<<<dim3(288), dim3(256), 0, stream>>>(w, wr);
    conv_mfma<<<dim3(16 * 112), dim3(512), 0, stream>>>(x, wr, bias, out);
}